// Round 6
// baseline (480.820 us; speedup 1.0000x reference)
//
#include <hip/hip_runtime.h>
#include <hip/hip_bf16.h>

// MultiLinear: y[b,g,o] = sum_i x[b,g,i] * W[g,o,i] + bias[g,o]
// B=4096, G=16, DIN=512, DOUT=512, fp32 in/out.
// R6: R4's 256x256/BK=64 reg-staged schedule, but SINGLE-buffered LDS (72 KB)
// -> 2 blocks/CU co-resident (grid 512 = one round). The co-resident block
// fills barrier/latency bubbles (R4/R5 were 1 block/CU, Occupancy 20%,
// all pipes <30% busy => latency-bound). One extra barrier per K-tile for
// the write-after-read hazard. bf16 MFMA 16x16x32, fused fp32->bf16 cvt.

#define BATCH 4096
#define NGRP  16
#define DIN   512
#define DOUT  512

#define BM 256
#define BN 256
#define BK 64
#define NT (DIN / BK)   // 8 K-steps
#define LDK 72          // padded: 144 B row stride

typedef __bf16 bf16x8 __attribute__((ext_vector_type(8)));
typedef float  f32x4  __attribute__((ext_vector_type(4)));

__global__ __launch_bounds__(512, 4)
void MultiLinear_48498770706571_kernel(const float* __restrict__ X,
                                       const float* __restrict__ Wt,
                                       const float* __restrict__ Bias,
                                       float* __restrict__ Y) {
    // 512 blocks / 8 XCDs = 64 consecutive tiles (2 full groups) per XCD.
    const int bid = (blockIdx.x & 7) * 64 + (blockIdx.x >> 3);
    const int g   = bid >> 5;          // 32 tiles per group (16 m x 2 n)
    const int mt  = (bid >> 1) & 15;
    const int nt  = bid & 1;
    const int bm0 = mt * BM;
    const int bn0 = nt * BN;

    __shared__ __bf16 As[BM][LDK];   // 36 KB
    __shared__ __bf16 Bs[BN][LDK];   // 36 KB  (total 72 KB -> 2 blocks/CU)

    const int tid  = threadIdx.x;
    const int lane = tid & 63;
    const int w    = tid >> 6;        // 0..7
    const int wm   = (w >> 2) * 128;  // {0,128}
    const int wn   = (w & 3) * 64;    // {0,64,128,192}

    // staging: 128 rows/pass (4 threads/row, 16 floats each), 2 passes.
    const int srow = tid >> 2;        // 0..127
    const int scol = (tid & 3) * 16;  // 0,16,32,48

    const float* pA = X + (size_t)(bm0 + srow) * (NGRP * DIN) + g * DIN + scol;
    const float* pB = Wt + (size_t)g * (DOUT * DIN) + (size_t)(bn0 + srow) * DIN + scol;
    const size_t strideA = (size_t)128 * (NGRP * DIN);
    const size_t strideB = (size_t)128 * DIN;

    f32x4 ra[2][4], rb[2][4];   // 64 VGPRs in flight

#define ISSUE_LOADS(k0)                                                    \
    do {                                                                   \
        const f32x4* qa0 = (const f32x4*)(pA + (k0));                      \
        const f32x4* qa1 = (const f32x4*)(pA + strideA + (k0));            \
        const f32x4* qb0 = (const f32x4*)(pB + (k0));                      \
        const f32x4* qb1 = (const f32x4*)(pB + strideB + (k0));            \
        ra[0][0] = qa0[0]; ra[0][1] = qa0[1]; ra[0][2] = qa0[2]; ra[0][3] = qa0[3]; \
        ra[1][0] = qa1[0]; ra[1][1] = qa1[1]; ra[1][2] = qa1[2]; ra[1][3] = qa1[3]; \
        rb[0][0] = qb0[0]; rb[0][1] = qb0[1]; rb[0][2] = qb0[2]; rb[0][3] = qb0[3]; \
        rb[1][0] = qb1[0]; rb[1][1] = qb1[1]; rb[1][2] = qb1[2]; rb[1][3] = qb1[3]; \
    } while (0)

#define CVT_WRITE()                                                        \
    do {                                                                   \
        _Pragma("unroll")                                                  \
        for (int p = 0; p < 2; ++p) {                                      \
            bf16x8 v0, v1, u0, u1;                                         \
            _Pragma("unroll")                                              \
            for (int j = 0; j < 4; ++j) {                                  \
                v0[j] = (__bf16)ra[p][0][j]; v0[j + 4] = (__bf16)ra[p][1][j]; \
                v1[j] = (__bf16)ra[p][2][j]; v1[j + 4] = (__bf16)ra[p][3][j]; \
                u0[j] = (__bf16)rb[p][0][j]; u0[j + 4] = (__bf16)rb[p][1][j]; \
                u1[j] = (__bf16)rb[p][2][j]; u1[j + 4] = (__bf16)rb[p][3][j]; \
            }                                                              \
            const int row = p * 128 + srow;                                \
            *(bf16x8*)&As[row][scol]     = v0;                             \
            *(bf16x8*)&As[row][scol + 8] = v1;                             \
            *(bf16x8*)&Bs[row][scol]     = u0;                             \
            *(bf16x8*)&Bs[row][scol + 8] = u1;                             \
        }                                                                  \
    } while (0)

    f32x4 acc[8][4];
#pragma unroll
    for (int mi = 0; mi < 8; ++mi)
#pragma unroll
        for (int ni = 0; ni < 4; ++ni) acc[mi][ni] = f32x4{0.f, 0.f, 0.f, 0.f};

    // prologue: stage kt=0 (one-time exposed vmcnt wait)
    ISSUE_LOADS(0);
    CVT_WRITE();

    for (int kt = 0; kt < NT; ++kt) {
        // issue next K-step's loads early; global loads use vmcnt only, so
        // they stay in flight across the lgkm-only barrier below.
        if (kt + 1 < NT) ISSUE_LOADS((kt + 1) * BK);
        // drain own ds_writes (visibility), then barrier -> LDS tile ready.
        asm volatile("s_waitcnt lgkmcnt(0)" ::: "memory");
        __builtin_amdgcn_s_barrier();

#pragma unroll
        for (int kk = 0; kk < BK; kk += 32) {
            const int ko = kk + (lane >> 4) * 8;
            bf16x8 af[8], bfr[4];
#pragma unroll
            for (int mi = 0; mi < 8; ++mi)
                af[mi] = *(const bf16x8*)&As[wm + mi * 16 + (lane & 15)][ko];
#pragma unroll
            for (int ni = 0; ni < 4; ++ni)
                bfr[ni] = *(const bf16x8*)&Bs[wn + ni * 16 + (lane & 15)][ko];
#pragma unroll
            for (int mi = 0; mi < 8; ++mi)
#pragma unroll
                for (int ni = 0; ni < 4; ++ni)
                    acc[mi][ni] = __builtin_amdgcn_mfma_f32_16x16x32_bf16(
                        af[mi], bfr[ni], acc[mi][ni], 0, 0, 0);
        }

        if (kt + 1 < NT) {
            // all waves' ds_reads must have returned before we overwrite the
            // single buffer: drain own reads, barrier, then cvt+write.
            asm volatile("s_waitcnt lgkmcnt(0)" ::: "memory");
            __builtin_amdgcn_s_barrier();
            CVT_WRITE();   // vmcnt wait on ra/rb lands here, ~1 phase after issue
        }
    }

    // epilogue: C/D layout col = lane&15, row = (lane>>4)*4 + j (verified R1)
    const int r0 = (lane >> 4) * 4;
    const int c  = lane & 15;
    float bias_n[4];
#pragma unroll
    for (int ni = 0; ni < 4; ++ni)
        bias_n[ni] = Bias[g * DOUT + bn0 + wn + ni * 16 + c];
#pragma unroll
    for (int mi = 0; mi < 8; ++mi) {
#pragma unroll
        for (int j = 0; j < 4; ++j) {
            const int row = bm0 + wm + mi * 16 + r0 + j;
            float* yrow = Y + (size_t)row * (NGRP * DOUT) + g * DOUT + bn0 + wn;
#pragma unroll
            for (int ni = 0; ni < 4; ++ni)
                yrow[ni * 16 + c] = acc[mi][ni][j] + bias_n[ni];
        }
    }
#undef ISSUE_LOADS
#undef CVT_WRITE
}

extern "C" void kernel_launch(void* const* d_in, const int* in_sizes, int n_in,
                              void* d_out, int out_size, void* d_ws, size_t ws_size,
                              hipStream_t stream) {
    const float* X    = (const float*)d_in[0];
    const float* Wt   = (const float*)d_in[1];
    const float* Bias = (const float*)d_in[2];
    float* Y          = (float*)d_out;

    const int grid = NGRP * (BATCH / BM) * (DOUT / BN);  // 512
    MultiLinear_48498770706571_kernel<<<grid, 512, 0, stream>>>(X, Wt, Bias, Y);
}

// Round 7
// 112.684 us; speedup vs baseline: 4.2670x; 4.2670x over previous
//
#include <hip/hip_runtime.h>
#include <hip/hip_bf16.h>

// MultiLinear: y[b,g,o] = sum_i x[b,g,i] * W[g,o,i] + bias[g,o]
// B=4096, G=16, DIN=512, DOUT=512, fp32 in/out.
// R7: occupancy-first config. 128x128 tile, 256 thr (4 waves 2x2, wave-tile
// 64x64 -> acc 64 AGPR), BK=32 (staging 32 fl/thread), double-buffered LDS
// 41 KB. Total regs ~140 -> 3 waves/SIMD bin (170) -> 3 blocks/CU = 12
// waves/CU, three INDEPENDENT blocks fill each other's barrier/vmcnt bubbles
// (R4/R5/R6 showed 1 lockstep block/CU leaves all pipes <25% busy).
// R3-verified schedule: prefetch -> lgkm-only raw barrier -> compute ->
// cvt+write other buffer. XCD-chunked swizzle (R2-verified, FETCH 87 MB).

#define BATCH 4096
#define NGRP  16
#define DIN   512
#define DOUT  512

#define BM 128
#define BN 128
#define BK 32
#define NT (DIN / BK)   // 16 K-steps
#define LDK 40          // padded: 80 B row stride (2-way bank alias = free)

typedef __bf16 bf16x8 __attribute__((ext_vector_type(8)));
typedef float  f32x4  __attribute__((ext_vector_type(4)));

__global__ __launch_bounds__(256, 3)
void MultiLinear_48498770706571_kernel(const float* __restrict__ X,
                                       const float* __restrict__ Wt,
                                       const float* __restrict__ Bias,
                                       float* __restrict__ Y) {
    // 2048 blocks / 8 XCDs = 256 consecutive tiles (2 full groups) per XCD.
    const int bid = (blockIdx.x & 7) * 256 + (blockIdx.x >> 3);
    const int g   = bid >> 7;          // 128 tiles per group (32 m x 4 n)
    const int mt  = (bid >> 2) & 31;
    const int nt  = bid & 3;
    const int bm0 = mt * BM;
    const int bn0 = nt * BN;

    __shared__ __bf16 As[2][BM][LDK];  // 2*128*40*2B = 20.5 KB
    __shared__ __bf16 Bs[2][BN][LDK];  // total 41 KB -> LDS allows 3 blocks/CU

    const int tid  = threadIdx.x;
    const int lane = tid & 63;
    const int w    = tid >> 6;        // 0..3
    const int wm   = (w >> 1) * 64;   // {0,64}
    const int wn   = (w & 1) * 64;    // {0,64}
    const int l15  = lane & 15;
    const int kq   = (lane >> 4) * 8; // 0,8,16,24

    // staging: 2 threads/row, 16 floats each; 128 rows covered by 256 thr.
    const int srow = tid >> 1;        // 0..127
    const int scol = (tid & 1) * 16;  // 0 or 16

    const float* pA = X + (size_t)(bm0 + srow) * (NGRP * DIN) + g * DIN + scol;
    const float* pB = Wt + (size_t)g * (DOUT * DIN) + (size_t)(bn0 + srow) * DIN + scol;

    f32x4 ra[4], rb[4];   // 32 VGPRs in flight

#define ISSUE_LOADS(k0)                                                    \
    do {                                                                   \
        const f32x4* qa = (const f32x4*)(pA + (k0));                       \
        const f32x4* qb = (const f32x4*)(pB + (k0));                       \
        ra[0] = qa[0]; ra[1] = qa[1]; ra[2] = qa[2]; ra[3] = qa[3];        \
        rb[0] = qb[0]; rb[1] = qb[1]; rb[2] = qb[2]; rb[3] = qb[3];        \
    } while (0)

#define CVT_WRITE(buf)                                                     \
    do {                                                                   \
        bf16x8 va0, va1, vb0, vb1;                                         \
        _Pragma("unroll")                                                  \
        for (int j = 0; j < 4; ++j) {                                      \
            va0[j] = (__bf16)ra[0][j]; va0[j + 4] = (__bf16)ra[1][j];      \
            va1[j] = (__bf16)ra[2][j]; va1[j + 4] = (__bf16)ra[3][j];      \
            vb0[j] = (__bf16)rb[0][j]; vb0[j + 4] = (__bf16)rb[1][j];      \
            vb1[j] = (__bf16)rb[2][j]; vb1[j + 4] = (__bf16)rb[3][j];      \
        }                                                                  \
        *(bf16x8*)&As[buf][srow][scol]     = va0;                          \
        *(bf16x8*)&As[buf][srow][scol + 8] = va1;                          \
        *(bf16x8*)&Bs[buf][srow][scol]     = vb0;                          \
        *(bf16x8*)&Bs[buf][srow][scol + 8] = vb1;                          \
    } while (0)

    f32x4 acc[4][4];
#pragma unroll
    for (int mi = 0; mi < 4; ++mi)
#pragma unroll
        for (int ni = 0; ni < 4; ++ni) acc[mi][ni] = f32x4{0.f, 0.f, 0.f, 0.f};

    // prologue: stage kt=0 into buf 0 (one-time exposed vmcnt wait)
    ISSUE_LOADS(0);
    CVT_WRITE(0);

    for (int kt = 0; kt < NT; ++kt) {
        // prefetch next K-step before the barrier; raw barrier is lgkm-only,
        // so these global loads stay in flight across it.
        if (kt + 1 < NT) ISSUE_LOADS((kt + 1) * BK);
        asm volatile("s_waitcnt lgkmcnt(0)" ::: "memory");
        __builtin_amdgcn_s_barrier();

        const int cur = kt & 1;
        bf16x8 af[4], bfr[4];
#pragma unroll
        for (int mi = 0; mi < 4; ++mi)
            af[mi] = *(const bf16x8*)&As[cur][wm + mi * 16 + l15][kq];
#pragma unroll
        for (int ni = 0; ni < 4; ++ni)
            bfr[ni] = *(const bf16x8*)&Bs[cur][wn + ni * 16 + l15][kq];
#pragma unroll
        for (int mi = 0; mi < 4; ++mi)
#pragma unroll
            for (int ni = 0; ni < 4; ++ni)
                acc[mi][ni] = __builtin_amdgcn_mfma_f32_16x16x32_bf16(
                    af[mi], bfr[ni], acc[mi][ni], 0, 0, 0);

        // cvt + write NEXT K-step into the other buffer. Safe: every wave
        // drained its own ds_reads (lgkmcnt(0)) before the barrier above, so
        // buf^1's previous readers are done. vmcnt wait on ra/rb lands here,
        // ~1 K-step after issue, hidden under the compute of other blocks.
        if (kt + 1 < NT) CVT_WRITE((kt + 1) & 1);
    }

    // epilogue: C/D layout col = lane&15, row = (lane>>4)*4 + j (verified R1)
    const int r0 = (lane >> 4) * 4;
    const int c  = lane & 15;
    float bias_n[4];
#pragma unroll
    for (int ni = 0; ni < 4; ++ni)
        bias_n[ni] = Bias[g * DOUT + bn0 + wn + ni * 16 + c];
#pragma unroll
    for (int mi = 0; mi < 4; ++mi) {
#pragma unroll
        for (int j = 0; j < 4; ++j) {
            const int row = bm0 + wm + mi * 16 + r0 + j;
            float* yrow = Y + (size_t)row * (NGRP * DOUT) + g * DOUT + bn0 + wn;
#pragma unroll
            for (int ni = 0; ni < 4; ++ni)
                yrow[ni * 16 + c] = acc[mi][ni][j] + bias_n[ni];
        }
    }
#undef ISSUE_LOADS
#undef CVT_WRITE
}

extern "C" void kernel_launch(void* const* d_in, const int* in_sizes, int n_in,
                              void* d_out, int out_size, void* d_ws, size_t ws_size,
                              hipStream_t stream) {
    const float* X    = (const float*)d_in[0];
    const float* Wt   = (const float*)d_in[1];
    const float* Bias = (const float*)d_in[2];
    float* Y          = (float*)d_out;

    const int grid = NGRP * (BATCH / BM) * (DOUT / BN);  // 16*32*4 = 2048
    MultiLinear_48498770706571_kernel<<<grid, 256, 0, stream>>>(X, Wt, Bias, Y);
}